// Round 3
// baseline (79.981 us; speedup 1.0000x reference)
//
#include <hip/hip_runtime.h>
#include <hip/hip_bf16.h>
#include <cstdint>
#include <cstddef>

// BesselKANLayer: y[b,o] = sum_{i,d} bessel_d(tanh(x[b,i])) * C[i,o,d]
// b0 == 1 folded into bias[o] = sum_i C[i,o,0]; GEMM over K = 3*1024.
// GEMM: BM=256 BN=128 BK=64, 512 thr (8 waves 4Mx2N, per-wave 64x64),
// triple-buffered LDS (144KB), counted vmcnt(6), XOR bank swizzle,
// 2-phase-per-K-tile schedule (T3): {8 ds_read | 3 stage | bar | lgkm0 |
// setprio1 | 16 MFMA | setprio0 | bar} per phase.

#define BATCH   8192
#define IN_DIM  1024
#define OUT_DIM 1024
#define KDIM    3072
#define NT      48            // KDIM/64 K-tiles
#define BM      256
#define BN      128
#define LDS_TILE 24576        // shorts per buffer: A 256*64=16384 + B 128*64=8192

typedef __attribute__((ext_vector_type(4))) float f32x4;
typedef __attribute__((ext_vector_type(8))) short bf16x8;

static __device__ __forceinline__ short f2bf(float f) {
    uint32_t u = __float_as_uint(f);
    u += 0x7fffu + ((u >> 16) & 1u);
    return (short)(u >> 16);
}

// ---------------- prep: basis matrix A [8192][3072] bf16 ----------------
__global__ __launch_bounds__(256) void prep_basis(const float* __restrict__ x,
                                                  short* __restrict__ A) {
    int idx = blockIdx.x * 256 + threadIdx.x;
    int b = idx >> 8;
    int i = (idx & 255) << 2;
    const float4 xv = *reinterpret_cast<const float4*>(&x[(size_t)b * IN_DIM + i]);
    float xs[4] = {xv.x, xv.y, xv.z, xv.w};
    short o1[4], o2[4], o3[4];
#pragma unroll
    for (int j = 0; j < 4; ++j) {
        float t  = tanhf(xs[j]);
        float b1 = t + 1.0f;
        float b2 = 3.0f * t * b1 + 1.0f;
        float b3 = 5.0f * t * b2 + b1;
        o1[j] = f2bf(b1); o2[j] = f2bf(b2); o3[j] = f2bf(b3);
    }
    short* row = A + (size_t)b * KDIM;
    *reinterpret_cast<short4*>(&row[i])              = make_short4(o1[0], o1[1], o1[2], o1[3]);
    *reinterpret_cast<short4*>(&row[IN_DIM + i])     = make_short4(o2[0], o2[1], o2[2], o2[3]);
    *reinterpret_cast<short4*>(&row[2 * IN_DIM + i]) = make_short4(o3[0], o3[1], o3[2], o3[3]);
}

// -------- prep: Bt [1024][3072] bf16 transpose + bias[o] = sum_i C[i][o][0] --------
__global__ __launch_bounds__(256) void prep_coeffs(const float* __restrict__ C,
                                                   short* __restrict__ Bt,
                                                   float* __restrict__ bias) {
    __shared__ short tile[3][32][33];
    __shared__ float red[8][32];
    const int i0 = blockIdx.x * 32;
    const int o0 = blockIdx.y * 32;
    const int t  = threadIdx.x;
    const int lo = t & 31;
    const int li = t >> 5;   // 0..7
    float part = 0.0f;
#pragma unroll
    for (int r = 0; r < 4; ++r) {
        int i = li + r * 8;
        const float4 c4 = *reinterpret_cast<const float4*>(
            &C[((size_t)(i0 + i) * OUT_DIM + (o0 + lo)) * 4]);
        tile[0][i][lo] = f2bf(c4.y);
        tile[1][i][lo] = f2bf(c4.z);
        tile[2][i][lo] = f2bf(c4.w);
        part += c4.x;
    }
    red[li][lo] = part;
    __syncthreads();
#pragma unroll
    for (int r = 0; r < 4; ++r) {
        int o = (t >> 5) + r * 8;
        int i = t & 31;
#pragma unroll
        for (int d = 0; d < 3; ++d)
            Bt[(size_t)(o0 + o) * KDIM + d * IN_DIM + (i0 + i)] = tile[d][i][o];
    }
    if (t < 32) {
        float s = 0.0f;
#pragma unroll
        for (int k = 0; k < 8; ++k) s += red[k][t];
        atomicAdd(&bias[o0 + t], s);
    }
}

// ---------------- GEMM: out = A * Bt^T + bias ----------------
__global__ __launch_bounds__(512, 2) void gemm_kan(
    const short* __restrict__ A,     // [BATCH][KDIM]
    const short* __restrict__ Bt,    // [OUT_DIM][KDIM]
    const float* __restrict__ bias,  // [OUT_DIM]
    float* __restrict__ out)         // [BATCH][OUT_DIM]
{
    extern __shared__ short lds[];   // 3 * LDS_TILE shorts = 144 KB

    const int tid  = threadIdx.x;
    const int lane = tid & 63;
    const int wid  = tid >> 6;   // 0..7
    const int wm   = wid >> 1;   // 0..3 (M)
    const int wn   = wid & 1;    // 0..1 (N)

    // XCD-aware swizzle: XCD k gets 32 consecutive logical blocks = 4 A-rows x 8 cols
    const int bid  = blockIdx.x;          // 0..255
    const int swz  = (bid & 7) * 32 + (bid >> 3);
    const int brow = (swz >> 3) * BM;
    const int bcol = (swz & 7) * BN;

    const int l15 = lane & 15, lh = lane >> 4, l7 = lane & 7;
    const int pc0 = lh ^ l7;            // phys chunk for kk=0
    const int pc1 = pc0 ^ 4;            // kk=1

    // fragment LDS offsets (shorts), swizzled: byte chunk ^= (row & 7)
    int aoff[4][2], boff[4][2];
#pragma unroll
    for (int mi = 0; mi < 4; ++mi) {
        int r = wm * 64 + mi * 16 + l15;
        aoff[mi][0] = r * 64 + pc0 * 8;
        aoff[mi][1] = r * 64 + pc1 * 8;
    }
#pragma unroll
    for (int ni = 0; ni < 4; ++ni) {
        int r = wn * 64 + ni * 16 + l15;
        boff[ni][0] = 16384 + r * 64 + pc0 * 8;
        boff[ni][1] = 16384 + r * 64 + pc1 * 8;
    }

    // staging geometry: thread tid handles row srow (+s*64), phys chunk tid&7
    const int srow   = tid >> 3;                    // 0..63
    const int schunk = (tid & 7) ^ (srow & 7);      // inverse-swizzled source chunk

#define STAGE_A(KT_TILE, B, S)                                                        \
    __builtin_amdgcn_global_load_lds(                                                 \
        (const __attribute__((address_space(1))) void*)(                              \
            A + (size_t)(brow + (S) * 64 + srow) * KDIM + (KT_TILE) * 64 + schunk * 8), \
        (__attribute__((address_space(3))) void*)(                                    \
            lds + (B) * LDS_TILE + (S) * 4096 + tid * 8), 16, 0, 0)
#define STAGE_B(KT_TILE, B, S)                                                        \
    __builtin_amdgcn_global_load_lds(                                                 \
        (const __attribute__((address_space(1))) void*)(                              \
            Bt + (size_t)(bcol + (S) * 64 + srow) * KDIM + (KT_TILE) * 64 + schunk * 8), \
        (__attribute__((address_space(3))) void*)(                                    \
            lds + (B) * LDS_TILE + 16384 + (S) * 4096 + tid * 8), 16, 0, 0)

    // prologue: bias -> acc, stage tiles 0 and 1
    f32x4 acc[4][4];
#pragma unroll
    for (int ni = 0; ni < 4; ++ni) {
        float bv = bias[bcol + wn * 64 + ni * 16 + l15];
#pragma unroll
        for (int mi = 0; mi < 4; ++mi)
            acc[mi][ni] = (f32x4){bv, bv, bv, bv};
    }
    STAGE_A(0, 0, 0); STAGE_A(0, 0, 1); STAGE_A(0, 0, 2); STAGE_A(0, 0, 3);
    STAGE_B(0, 0, 0); STAGE_B(0, 0, 1);
    STAGE_A(1, 1, 0); STAGE_A(1, 1, 1); STAGE_A(1, 1, 2); STAGE_A(1, 1, 3);
    STAGE_B(1, 1, 0); STAGE_B(1, 1, 1);
    asm volatile("s_waitcnt vmcnt(6)" ::: "memory");   // tile 0 landed
    __builtin_amdgcn_s_barrier();

    int buf = 0, sbuf = 2;
    for (int t = 0; t < NT; ++t) {
        const short* Ab = lds + buf * LDS_TILE;
        const bool pf = (t + 2 < NT);
        bf16x8 af[4], bfr[4];

        // ================= phase 0 (kk = 0) =================
#pragma unroll
        for (int mi = 0; mi < 4; ++mi)
            af[mi] = *reinterpret_cast<const bf16x8*>(Ab + aoff[mi][0]);
#pragma unroll
        for (int ni = 0; ni < 4; ++ni)
            bfr[ni] = *reinterpret_cast<const bf16x8*>(Ab + boff[ni][0]);
        if (pf) { STAGE_A(t + 2, sbuf, 0); STAGE_A(t + 2, sbuf, 1); STAGE_A(t + 2, sbuf, 2); }
        __builtin_amdgcn_s_barrier();
        asm volatile("s_waitcnt lgkmcnt(0)" ::: "memory");
        __builtin_amdgcn_sched_barrier(0);
        __builtin_amdgcn_s_setprio(1);
#pragma unroll
        for (int mi = 0; mi < 4; ++mi)
#pragma unroll
            for (int ni = 0; ni < 4; ++ni)
                acc[mi][ni] = __builtin_amdgcn_mfma_f32_16x16x32_bf16(
                    af[mi], bfr[ni], acc[mi][ni], 0, 0, 0);
        __builtin_amdgcn_s_setprio(0);
        __builtin_amdgcn_s_barrier();

        // ================= phase 1 (kk = 1) =================
#pragma unroll
        for (int mi = 0; mi < 4; ++mi)
            af[mi] = *reinterpret_cast<const bf16x8*>(Ab + aoff[mi][1]);
#pragma unroll
        for (int ni = 0; ni < 4; ++ni)
            bfr[ni] = *reinterpret_cast<const bf16x8*>(Ab + boff[ni][1]);
        if (pf) { STAGE_A(t + 2, sbuf, 3); STAGE_B(t + 2, sbuf, 0); STAGE_B(t + 2, sbuf, 1); }
        // counted vmcnt once per K-tile: tile t+1's 6 loads drained, t+2's stay in flight
        if (pf) { asm volatile("s_waitcnt vmcnt(6)" ::: "memory"); }
        else    { asm volatile("s_waitcnt vmcnt(0)" ::: "memory"); }
        __builtin_amdgcn_s_barrier();
        asm volatile("s_waitcnt lgkmcnt(0)" ::: "memory");
        __builtin_amdgcn_sched_barrier(0);
        __builtin_amdgcn_s_setprio(1);
#pragma unroll
        for (int mi = 0; mi < 4; ++mi)
#pragma unroll
            for (int ni = 0; ni < 4; ++ni)
                acc[mi][ni] = __builtin_amdgcn_mfma_f32_16x16x32_bf16(
                    af[mi], bfr[ni], acc[mi][ni], 0, 0, 0);
        __builtin_amdgcn_s_setprio(0);
        __builtin_amdgcn_s_barrier();

        buf  = (buf  == 2) ? 0 : buf  + 1;
        sbuf = (sbuf == 2) ? 0 : sbuf + 1;
    }
#undef STAGE_A
#undef STAGE_B

    // epilogue: C/D layout col = lane&15, row = (lane>>4)*4 + reg
#pragma unroll
    for (int mi = 0; mi < 4; ++mi) {
#pragma unroll
        for (int r = 0; r < 4; ++r) {
            int row = brow + wm * 64 + mi * 16 + (lane >> 4) * 4 + r;
            float* orow = out + (size_t)row * OUT_DIM + bcol + wn * 64 + l15;
#pragma unroll
            for (int ni = 0; ni < 4; ++ni)
                orow[ni * 16] = acc[mi][ni][r];
        }
    }
}

extern "C" void kernel_launch(void* const* d_in, const int* in_sizes, int n_in,
                              void* d_out, int out_size, void* d_ws, size_t ws_size,
                              hipStream_t stream) {
    (void)in_sizes; (void)n_in; (void)out_size; (void)ws_size;
    const float* x      = (const float*)d_in[0];
    const float* coeffs = (const float*)d_in[1];
    float* out = (float*)d_out;

    char* ws = (char*)d_ws;
    short* A    = (short*)ws;                                        // 48 MB
    short* Bt   = (short*)(ws + (size_t)BATCH * KDIM * 2);           // 6 MB
    float* bias = (float*)(ws + (size_t)BATCH * KDIM * 2
                              + (size_t)OUT_DIM * KDIM * 2);         // 4 KB

    hipFuncSetAttribute((const void*)gemm_kan,
                        hipFuncAttributeMaxDynamicSharedMemorySize,
                        3 * LDS_TILE * (int)sizeof(short));

    hipMemsetAsync(bias, 0, OUT_DIM * sizeof(float), stream);
    hipLaunchKernelGGL(prep_basis, dim3(BATCH * IN_DIM / 4 / 256), dim3(256), 0, stream,
                       x, A);
    hipLaunchKernelGGL(prep_coeffs, dim3(IN_DIM / 32, OUT_DIM / 32), dim3(256), 0, stream,
                       coeffs, Bt, bias);
    hipLaunchKernelGGL(gemm_kan, dim3((BATCH / BM) * (OUT_DIM / BN)), dim3(512),
                       3 * LDS_TILE * sizeof(short), stream,
                       A, Bt, bias, out);
}